// Round 1
// baseline (541.703 us; speedup 1.0000x reference)
//
#include <hip/hip_runtime.h>
#include <math.h>

constexpr int NN    = 65536;   // nodes layer1
constexpr int NPGc  = 128;     // nodes per graph
constexpr int NG    = 512;     // graphs
constexpr int EPGc  = 2048;    // edges per graph
constexpr int ETOT  = 1048576; // total edges
constexpr int IND   = 11;
constexpr int HIDc  = 32;
constexpr int FD    = 128;     // HEADS*HID
constexpr int K1c   = 103;
constexpr int K2c   = 83;
constexpr int N2c   = NG * K1c; // 52736

__device__ __forceinline__ float lrelu(float x){ return x > 0.f ? x : 0.2f*x; }

// ---- projection: xp = x @ Wg  (row per block), plus per-head att dots ----
template<int KIN>
__global__ __launch_bounds__(128) void k_proj(const float* __restrict__ x,
    const float* __restrict__ Wg, const float* __restrict__ av_s, const float* __restrict__ av_d,
    float* __restrict__ xp, float* __restrict__ as_, float* __restrict__ ad_)
{
    int n = blockIdx.x, c = threadIdx.x;
    __shared__ float xL[KIN];
    __shared__ float xpL[FD];
    if (c < KIN) xL[c] = x[(size_t)n*KIN + c];
    __syncthreads();
    float acc = 0.f;
    for (int k = 0; k < KIN; k++) acc = fmaf(xL[k], Wg[k*FD + c], acc);
    xp[(size_t)n*FD + c] = acc;
    xpL[c] = acc;
    __syncthreads();
    if (c < 8) {
        int h = c & 3;
        const float* av = (c >= 4 ? av_d : av_s) + h*HIDc;
        float s = 0.f;
        for (int k = 0; k < HIDc; k++) s = fmaf(xpL[h*HIDc + k], av[k], s);
        if (c >= 4) ad_[(size_t)n*4 + h] = s; else as_[(size_t)n*4 + h] = s;
    }
}

// ---- GAT attention + aggregation, one graph per block ----
template<int NNODE, bool REMAP>
__global__ __launch_bounds__(256) void k_gat(const int* __restrict__ ei,
    const int* __restrict__ rankv, const float* __restrict__ xp,
    const float* __restrict__ as_, const float* __restrict__ ad_,
    const float* __restrict__ bias, float* __restrict__ outp)
{
    int g = blockIdx.x, t = threadIdx.x;
    __shared__ unsigned char srcL[EPGc];
    __shared__ unsigned char dstL[EPGc];
    __shared__ unsigned short bucket[EPGc];
    __shared__ float asL[NNODE][4], adL[NNODE][4], mL[NNODE][4], sL[NNODE][4];
    __shared__ int cnt[NNODE], off[NNODE + 1], cur[NNODE];
    __shared__ signed char rmap[NPGc];

    int baseOld = g * NPGc;
    int base    = g * NNODE;
    if constexpr (REMAP) {
        for (int n = t; n < NPGc; n += 256) rmap[n] = (signed char)rankv[baseOld + n];
    }
    for (int n = t; n < NNODE; n += 256) {
        cnt[n] = 0;
        for (int h = 0; h < 4; h++) {
            asL[n][h] = as_[(size_t)(base + n)*4 + h];
            adL[n][h] = ad_[(size_t)(base + n)*4 + h];
        }
    }
    __syncthreads();
    const int* srcG = ei + g * EPGc;
    const int* dstG = ei + ETOT + g * EPGc;
    for (int e = t; e < EPGc; e += 256) {
        int so = srcG[e] - baseOld, dO = dstG[e] - baseOld;
        if constexpr (REMAP) {
            int sn = rmap[so], dn = rmap[dO];
            if (sn >= 0 && dn >= 0) {
                srcL[e] = (unsigned char)sn; dstL[e] = (unsigned char)dn;
                atomicAdd(&cnt[dn], 1);
            } else dstL[e] = 255;
        } else {
            srcL[e] = (unsigned char)so; dstL[e] = (unsigned char)dO;
            atomicAdd(&cnt[dO], 1);
        }
    }
    __syncthreads();
    if (t == 0) { int r = 0; for (int n = 0; n < NNODE; n++) { off[n] = r; r += cnt[n]; } off[NNODE] = r; }
    __syncthreads();
    for (int n = t; n < NNODE; n += 256) cur[n] = off[n];
    __syncthreads();
    for (int e = t; e < EPGc; e += 256) {
        unsigned char d = dstL[e];
        bool ok = true;
        if constexpr (REMAP) ok = (d != 255);
        if (ok) { int p = atomicAdd(&cur[d], 1); bucket[p] = (unsigned short)e; }
    }
    __syncthreads();
    // deterministic within-bucket order (edge-index ascending)
    for (int n = t; n < NNODE; n += 256) {
        int lo = off[n], hi = off[n + 1];
        for (int i = lo + 1; i < hi; i++) {
            unsigned short v = bucket[i]; int j = i - 1;
            while (j >= lo && bucket[j] > v) { bucket[j + 1] = bucket[j]; j--; }
            bucket[j + 1] = v;
        }
    }
    __syncthreads();
    // online softmax stats per (node, head); self-loop seeds the state
    for (int p = t; p < NNODE * 4; p += 256) {
        int n = p >> 2, h = p & 3;
        float adn = adL[n][h];
        float m = lrelu(asL[n][h] + adn);
        float s = 1.f;
        int lo = off[n], hi = off[n + 1];
        for (int i = lo; i < hi; i++) {
            int sc = srcL[bucket[i]];
            float l = lrelu(asL[sc][h] + adn);
            if (l <= m) s += expf(l - m);
            else { s = s * expf(m - l) + 1.f; m = l; }
        }
        mL[n][h] = m; sL[n][h] = s;
    }
    __syncthreads();
    // weighted aggregation
    for (int p = t; p < NNODE * 4; p += 256) {
        int n = p >> 2, h = p & 3;
        float adn = adL[n][h];
        float m = mL[n][h];
        float inv = 1.f / (sL[n][h] + 1e-16f);
        float w0 = expf(lrelu(asL[n][h] + adn) - m);
        const float4* xr = (const float4*)(xp + (size_t)(base + n)*FD + h*HIDc);
        float4 acc[8];
        for (int q = 0; q < 8; q++) {
            float4 v = xr[q];
            acc[q].x = w0*v.x; acc[q].y = w0*v.y; acc[q].z = w0*v.z; acc[q].w = w0*v.w;
        }
        int lo = off[n], hi = off[n + 1];
        for (int i = lo; i < hi; i++) {
            int sc = srcL[bucket[i]];
            float w = expf(lrelu(asL[sc][h] + adn) - m);
            const float4* sr = (const float4*)(xp + (size_t)(base + sc)*FD + h*HIDc);
            for (int q = 0; q < 8; q++) {
                float4 v = sr[q];
                acc[q].x = fmaf(w, v.x, acc[q].x); acc[q].y = fmaf(w, v.y, acc[q].y);
                acc[q].z = fmaf(w, v.z, acc[q].z); acc[q].w = fmaf(w, v.w, acc[q].w);
            }
        }
        float4* orow = (float4*)(outp + (size_t)(base + n)*FD + h*HIDc);
        const float4* br = (const float4*)(bias + h*HIDc);
        for (int q = 0; q < 8; q++) {
            float4 b = br[q]; float4 r;
            r.x = fmaxf(fmaf(acc[q].x, inv, b.x), 0.f);
            r.y = fmaxf(fmaf(acc[q].y, inv, b.y), 0.f);
            r.z = fmaxf(fmaf(acc[q].z, inv, b.z), 0.f);
            r.w = fmaxf(fmaf(acc[q].w, inv, b.w), 0.f);
            orow[q] = r;
        }
    }
}

// ---- small linear: out[n,j] = in[n,:128] @ W[:,j] + b[j], j<32 ----
__global__ void k_lin(const float* __restrict__ in, const float* __restrict__ W,
                      const float* __restrict__ b, float* __restrict__ outp, int nrows)
{
    int idx = blockIdx.x * 256 + threadIdx.x;
    if (idx >= nrows * HIDc) return;
    int n = idx >> 5, j = idx & 31;
    const float* r = in + (size_t)n * FD;
    float acc = b[j];
    for (int k = 0; k < FD; k++) acc = fmaf(r[k], W[k*HIDc + j], acc);
    outp[idx] = acc;
}

// ---- top-k pool (+ fused graph max/mean readout) ----
template<int NIN, int KEEP>
__global__ __launch_bounds__(128) void k_pool(const float* __restrict__ ht,
    const float* __restrict__ pw, float* __restrict__ xnew, int* __restrict__ rankv,
    float* __restrict__ gfeat, const float* __restrict__ gprev)
{
    int g = blockIdx.x, t = threadIdx.x;
    __shared__ float scoreL[NIN];
    __shared__ float keptL[KEEP][HIDc];
    float ss = 0.f;
    for (int k = 0; k < HIDc; k++) ss = fmaf(pw[k], pw[k], ss);
    float nrm = sqrtf(ss);
    const float* r = ht + (size_t)(g * NIN + t) * HIDc;
    float val = 0.f;
    if (t < NIN) {
        float dot = 0.f;
        for (int k = 0; k < HIDc; k++) dot = fmaf(r[k], pw[k], dot);
        val = tanhf(dot / nrm);
        scoreL[t] = val;
    }
    __syncthreads();
    if (t < NIN) {
        int rank = 0; float si = val;
        for (int j = 0; j < NIN; j++) {
            float sj = scoreL[j];
            if (sj > si || (sj == si && j < t)) rank++;
        }
        if (rank < KEEP) {
            for (int k = 0; k < HIDc; k++) {
                float v = r[k] * val;
                keptL[rank][k] = v;
                if (xnew) xnew[(size_t)(g * KEEP + rank) * HIDc + k] = v;
            }
            if (rankv) rankv[g * NIN + t] = rank;
        } else if (rankv) rankv[g * NIN + t] = -1;
    }
    __syncthreads();
    if (t < HIDc) {
        float mx = -INFINITY, sm = 0.f;
        for (int i = 0; i < KEEP; i++) { float v = keptL[i][t]; mx = fmaxf(mx, v); sm += v; }
        float mean = sm / (float)KEEP;
        if (gprev) {
            gfeat[(size_t)g*64 + t]      = gprev[(size_t)g*64 + t] + mx;
            gfeat[(size_t)g*64 + 32 + t] = gprev[(size_t)g*64 + 32 + t] + mean;
        } else {
            gfeat[(size_t)g*64 + t]      = mx;
            gfeat[(size_t)g*64 + 32 + t] = mean;
        }
    }
}

// ---- MLP head: 64 -> 256 -> 1024 -> 1, one graph per block ----
__global__ __launch_bounds__(256) void k_mlp(const float* __restrict__ gsum,
    const float* __restrict__ W1, const float* __restrict__ b1,
    const float* __restrict__ W2, const float* __restrict__ b2,
    const float* __restrict__ W3, const float* __restrict__ b3,
    float* __restrict__ outp)
{
    int g = blockIdx.x, t = threadIdx.x;
    __shared__ float gL[64];
    __shared__ float h1L[256];
    __shared__ float h2L[1024];
    __shared__ float red[256];
    if (t < 64) gL[t] = gsum[(size_t)g*64 + t];
    __syncthreads();
    {
        float acc = b1[t];
        for (int i = 0; i < 64; i++) acc = fmaf(gL[i], W1[i*256 + t], acc);
        h1L[t] = fmaxf(acc, 0.f);
    }
    __syncthreads();
    for (int q = 0; q < 4; q++) {
        int o = t + q*256;
        float acc = b2[o];
        for (int i = 0; i < 256; i++) acc = fmaf(h1L[i], W2[i*1024 + o], acc);
        h2L[o] = fmaxf(acc, 0.f);
    }
    __syncthreads();
    float p = 0.f;
    for (int q = 0; q < 4; q++) { int o = t + q*256; p = fmaf(h2L[o], W3[o], p); }
    red[t] = p;
    __syncthreads();
    for (int s = 128; s > 0; s >>= 1) { if (t < s) red[t] += red[t + s]; __syncthreads(); }
    if (t == 0) outp[g] = red[0] + b3[0];
}

extern "C" void kernel_launch(void* const* d_in, const int* in_sizes, int n_in,
                              void* d_out, int out_size, void* d_ws, size_t ws_size,
                              hipStream_t stream)
{
    const float* x    = (const float*)d_in[0];
    const int*   ei   = (const int*)  d_in[1];
    const float* W_g1 = (const float*)d_in[4];
    const float* as1w = (const float*)d_in[5];
    const float* ad1w = (const float*)d_in[6];
    const float* b_g1 = (const float*)d_in[7];
    const float* W_t1 = (const float*)d_in[8];
    const float* b_t1 = (const float*)d_in[9];
    const float* pw1  = (const float*)d_in[10];
    const float* W_g2 = (const float*)d_in[11];
    const float* as2w = (const float*)d_in[12];
    const float* ad2w = (const float*)d_in[13];
    const float* b_g2 = (const float*)d_in[14];
    const float* W_t2 = (const float*)d_in[15];
    const float* b_t2 = (const float*)d_in[16];
    const float* pw2  = (const float*)d_in[17];
    const float* W_l1 = (const float*)d_in[18];
    const float* b_l1 = (const float*)d_in[19];
    const float* W_l2 = (const float*)d_in[20];
    const float* b_l2 = (const float*)d_in[21];
    const float* W_l3 = (const float*)d_in[22];
    const float* b_l3 = (const float*)d_in[23];
    float* out = (float*)d_out;

    char* ws = (char*)d_ws;
    size_t off = 0;
    auto alloc = [&](size_t elems) -> float* {
        float* p = (float*)(ws + off);
        off += ((elems * 4 + 255) / 256) * 256;
        return p;
    };
    float* xp1  = alloc((size_t)NN * FD);     // reused as hg2
    float* as1  = alloc((size_t)NN * 4);      // reused as as2
    float* ad1  = alloc((size_t)NN * 4);      // reused as ad2
    float* hg1  = alloc((size_t)NN * FD);     // reused as xp2
    float* ht1  = alloc((size_t)NN * HIDc);   // reused as ht2
    float* x2   = alloc((size_t)N2c * HIDc);
    int*   rank1= (int*)alloc((size_t)NN);
    float* g1   = alloc((size_t)NG * 64);
    float* gsum = alloc((size_t)NG * 64);
    float* xp2 = hg1;
    float* as2 = as1; float* ad2 = ad1;
    float* hg2 = xp1;
    float* ht2 = ht1;

    k_proj<IND><<<NN, 128, 0, stream>>>(x, W_g1, as1w, ad1w, xp1, as1, ad1);
    k_gat<NPGc, false><<<NG, 256, 0, stream>>>(ei, nullptr, xp1, as1, ad1, b_g1, hg1);
    k_lin<<<(NN * HIDc + 255) / 256, 256, 0, stream>>>(hg1, W_t1, b_t1, ht1, NN);
    k_pool<NPGc, K1c><<<NG, 128, 0, stream>>>(ht1, pw1, x2, rank1, g1, nullptr);
    k_proj<HIDc><<<N2c, 128, 0, stream>>>(x2, W_g2, as2w, ad2w, xp2, as2, ad2);
    k_gat<K1c, true><<<NG, 256, 0, stream>>>(ei, rank1, xp2, as2, ad2, b_g2, hg2);
    k_lin<<<(N2c * HIDc + 255) / 256, 256, 0, stream>>>(hg2, W_t2, b_t2, ht2, N2c);
    k_pool<K1c, K2c><<<NG, 128, 0, stream>>>(ht2, pw2, nullptr, nullptr, gsum, g1);
    k_mlp<<<NG, 256, 0, stream>>>(gsum, W_l1, b_l1, W_l2, b_l2, W_l3, b_l3, out);
}

// Round 2
// 374.657 us; speedup vs baseline: 1.4459x; 1.4459x over previous
//
#include <hip/hip_runtime.h>
#include <math.h>

constexpr int NN    = 65536;   // nodes layer1
constexpr int NPGc  = 128;     // nodes per graph
constexpr int NG    = 512;     // graphs
constexpr int EPGc  = 2048;    // edges per graph
constexpr int ETOT  = 1048576; // total edges
constexpr int IND   = 11;
constexpr int HIDc  = 32;
constexpr int FD    = 128;     // HEADS*HID
constexpr int K1c   = 103;
constexpr int K2c   = 83;
constexpr int N2c   = NG * K1c; // 52736

__device__ __forceinline__ float lrelu(float x){ return x > 0.f ? x : 0.2f*x; }

// ---- fold attention vectors through Wg:  Ws[k][h] = sum_j Wg[k][h*32+j]*av[h*32+j]
template<int KIN>
__global__ void k_fold(const float* __restrict__ Wg, const float* __restrict__ avs,
                       const float* __restrict__ avd, float* __restrict__ WsS, float* __restrict__ WsD)
{
    int tt = threadIdx.x;
    if (tt < KIN * 4) {
        int k = tt >> 2, h = tt & 3;
        float s = 0.f, d = 0.f;
        for (int j = 0; j < HIDc; j++) {
            float w = Wg[k*FD + h*HIDc + j];
            s = fmaf(w, avs[h*HIDc + j], s);
            d = fmaf(w, avd[h*HIDc + j], d);
        }
        WsS[tt] = s; WsD[tt] = d;
    }
}

// ---- projection: 32 nodes per block, W in LDS; att dots via folded Ws ----
template<int KIN>
__global__ __launch_bounds__(256) void k_proj(const float* __restrict__ x,
    const float* __restrict__ Wg, const float* __restrict__ WsS, const float* __restrict__ WsD,
    float* __restrict__ xp, float* __restrict__ as_, float* __restrict__ ad_)
{
    int t = threadIdx.x;
    int rowbase = blockIdx.x * 32;
    __shared__ float WL[KIN * FD];
    __shared__ float xL[32 * KIN];
    __shared__ float WsSL[KIN * 4], WsDL[KIN * 4];
    for (int i = t; i < KIN * FD; i += 256) WL[i] = Wg[i];
    for (int i = t; i < 32 * KIN; i += 256) xL[i] = x[(size_t)rowbase * KIN + i];
    if (t < KIN * 4) { WsSL[t] = WsS[t]; WsDL[t] = WsD[t]; }
    __syncthreads();
    int nodeHalf = t >> 7, c = t & 127;
    #pragma unroll 4
    for (int p = 0; p < 16; p++) {
        int node = p * 2 + nodeHalf;
        float acc = 0.f;
        #pragma unroll
        for (int k = 0; k < KIN; k++) acc = fmaf(xL[node*KIN + k], WL[k*FD + c], acc);
        xp[((size_t)rowbase + node) * FD + c] = acc;
    }
    if (t < 128) {
        int n = t >> 2, h = t & 3;
        float s = 0.f, d = 0.f;
        #pragma unroll
        for (int k = 0; k < KIN; k++) {
            float xv = xL[n*KIN + k];
            s = fmaf(xv, WsSL[k*4 + h], s);
            d = fmaf(xv, WsDL[k*4 + h], d);
        }
        as_[((size_t)rowbase + n)*4 + h] = s;
        ad_[((size_t)rowbase + n)*4 + h] = d;
    }
}

// ---- GAT: one block per (graph, head); xp slice + attention weights in LDS ----
template<int NNODE, bool REMAP>
__global__ __launch_bounds__(256) void k_gat(const int* __restrict__ ei,
    const int* __restrict__ rankv, const float* __restrict__ xp,
    const float* __restrict__ as_, const float* __restrict__ ad_,
    const float* __restrict__ bias, float* __restrict__ outp)
{
    int g = blockIdx.x, h = blockIdx.y, t = threadIdx.x;
    __shared__ __align__(16) float xpL[NNODE * HIDc];
    __shared__ float alphaL[EPGc];
    __shared__ unsigned short bucket[EPGc];
    __shared__ float selfW[NNODE];
    __shared__ float asL[NNODE], adL[NNODE];
    __shared__ int cnt[NNODE], cur[NNODE], off[NNODE + 1];
    __shared__ signed char rmap[NPGc];
    __shared__ float bL[HIDc];

    int baseOld = g * NPGc;
    int base    = g * NNODE;
    if constexpr (REMAP) {
        if (t < NPGc) rmap[t] = (signed char)rankv[baseOld + t];
    }
    if (t < 8) ((float4*)bL)[t] = ((const float4*)(bias + h*HIDc))[t];
    for (int n = t; n < NNODE; n += 256) {
        cnt[n] = 0;
        asL[n] = as_[(size_t)(base + n)*4 + h];
        adL[n] = ad_[(size_t)(base + n)*4 + h];
    }
    // stage xp head-slice into LDS
    for (int idx = t; idx < NNODE * 8; idx += 256) {
        int n = idx >> 3, c4 = idx & 7;
        ((float4*)xpL)[n*8 + c4] =
            *(const float4*)(xp + (size_t)(base + n)*FD + h*HIDc + c4*4);
    }
    __syncthreads();
    const int* dstG = ei + ETOT + g * EPGc;
    // pass 1: in-degree counts (src is structural: src_local = e>>4)
    for (int e = t; e < EPGc; e += 256) {
        int dO = dstG[e] - baseOld;
        if constexpr (REMAP) {
            int sn = rmap[e >> 4], dn = rmap[dO];
            if (sn >= 0 && dn >= 0) atomicAdd(&cnt[dn], 1);
        } else {
            atomicAdd(&cnt[dO], 1);
        }
    }
    __syncthreads();
    // exclusive scan -> off
    if (t < NNODE) cur[t] = cnt[t];
    __syncthreads();
    for (int d = 1; d < NNODE; d <<= 1) {
        int v = 0;
        if (t < NNODE && t >= d) v = cur[t - d];
        __syncthreads();
        if (t < NNODE) cur[t] += v;
        __syncthreads();
    }
    if (t < NNODE) { off[t] = cur[t] - cnt[t]; if (t == NNODE - 1) off[NNODE] = cur[t]; }
    __syncthreads();
    if (t < NNODE) cur[t] = off[t];
    __syncthreads();
    // pass 2: scatter src ids into dst-buckets (order within bucket is arbitrary;
    // only affects last-ulp rounding of the softmax sums)
    for (int e = t; e < EPGc; e += 256) {
        int dO = dstG[e] - baseOld;
        if constexpr (REMAP) {
            int sn = rmap[e >> 4], dn = rmap[dO];
            if (sn >= 0 && dn >= 0) { int p = atomicAdd(&cur[dn], 1); bucket[p] = (unsigned short)sn; }
        } else {
            int p = atomicAdd(&cur[dO], 1); bucket[p] = (unsigned short)(e >> 4);
        }
    }
    __syncthreads();
    // per-node softmax stats, then normalized weights into alphaL / selfW
    for (int n = t; n < NNODE; n += 256) {
        float adn = adL[n];
        int lo = off[n], hi = off[n + 1];
        float m = -3.0e38f, s = 0.f;
        for (int i = lo; i < hi; i++) {
            float l = lrelu(asL[bucket[i]] + adn);
            if (l <= m) s += expf(l - m);
            else { s = s * expf(m - l) + 1.f; m = l; }
        }
        float lself = lrelu(asL[n] + adn);
        if (lself <= m) s += expf(lself - m);
        else { s = s * expf(m - lself) + 1.f; m = lself; }
        float inv = 1.f / (s + 1e-16f);
        for (int i = lo; i < hi; i++) {
            float l = lrelu(asL[bucket[i]] + adn);
            alphaL[i] = expf(l - m) * inv;
        }
        selfW[n] = expf(lself - m) * inv;
    }
    __syncthreads();
    // aggregation: thread item = (node, float4 chunk), all reads from LDS
    for (int p = t; p < NNODE * 8; p += 256) {
        int n = p >> 3, c4 = p & 7;
        float4 acc;
        float w0 = selfW[n];
        float4 v = ((const float4*)xpL)[n*8 + c4];
        acc.x = w0*v.x; acc.y = w0*v.y; acc.z = w0*v.z; acc.w = w0*v.w;
        int lo = off[n], hi = off[n + 1];
        for (int i = lo; i < hi; i++) {
            float w = alphaL[i];
            int sc = bucket[i];
            float4 u = ((const float4*)xpL)[sc*8 + c4];
            acc.x = fmaf(w, u.x, acc.x); acc.y = fmaf(w, u.y, acc.y);
            acc.z = fmaf(w, u.z, acc.z); acc.w = fmaf(w, u.w, acc.w);
        }
        float4 bb = ((const float4*)bL)[c4];
        float4 r;
        r.x = fmaxf(acc.x + bb.x, 0.f); r.y = fmaxf(acc.y + bb.y, 0.f);
        r.z = fmaxf(acc.z + bb.z, 0.f); r.w = fmaxf(acc.w + bb.w, 0.f);
        *(float4*)(outp + (size_t)(base + n)*FD + h*HIDc + c4*4) = r;
    }
}

// ---- linear 128->32: 32 rows/block, 4 rows/thread, broadcast W via L1 ----
__global__ __launch_bounds__(256) void k_lin(const float* __restrict__ in,
    const float* __restrict__ W, const float* __restrict__ b, float* __restrict__ outp)
{
    int j = threadIdx.x & 31, rg = threadIdx.x >> 5;
    int r0 = blockIdx.x * 32 + rg * 4;
    const float* i0 = in + (size_t)r0 * FD;
    float bj = b[j];
    float a0 = bj, a1 = bj, a2 = bj, a3 = bj;
    #pragma unroll 4
    for (int k = 0; k < FD; k++) {
        float w = W[k*HIDc + j];
        a0 = fmaf(i0[k],        w, a0);
        a1 = fmaf(i0[FD + k],   w, a1);
        a2 = fmaf(i0[2*FD + k], w, a2);
        a3 = fmaf(i0[3*FD + k], w, a3);
    }
    size_t ob = (size_t)r0 * HIDc + j;
    outp[ob] = a0; outp[ob + 32] = a1; outp[ob + 64] = a2; outp[ob + 96] = a3;
}

// ---- top-k pool (+ fused graph max/mean readout) ----
template<int NIN, int KEEP>
__global__ __launch_bounds__(128) void k_pool(const float* __restrict__ ht,
    const float* __restrict__ pw, float* __restrict__ xnew, int* __restrict__ rankv,
    float* __restrict__ gfeat, const float* __restrict__ gprev)
{
    int g = blockIdx.x, t = threadIdx.x;
    __shared__ float scoreL[NIN];
    __shared__ float keptL[KEEP][HIDc];
    float ss = 0.f;
    for (int k = 0; k < HIDc; k++) ss = fmaf(pw[k], pw[k], ss);
    float nrm = sqrtf(ss);
    const float* r = ht + (size_t)(g * NIN + t) * HIDc;
    float val = 0.f;
    if (t < NIN) {
        float dot = 0.f;
        for (int k = 0; k < HIDc; k++) dot = fmaf(r[k], pw[k], dot);
        val = tanhf(dot / nrm);
        scoreL[t] = val;
    }
    __syncthreads();
    if (t < NIN) {
        int rank = 0; float si = val;
        for (int j = 0; j < NIN; j++) {
            float sj = scoreL[j];
            if (sj > si || (sj == si && j < t)) rank++;
        }
        if (rank < KEEP) {
            for (int k = 0; k < HIDc; k++) {
                float v = r[k] * val;
                keptL[rank][k] = v;
                if (xnew) xnew[(size_t)(g * KEEP + rank) * HIDc + k] = v;
            }
            if (rankv) rankv[g * NIN + t] = rank;
        } else if (rankv) rankv[g * NIN + t] = -1;
    }
    __syncthreads();
    if (t < HIDc) {
        float mx = -INFINITY, sm = 0.f;
        for (int i = 0; i < KEEP; i++) { float v = keptL[i][t]; mx = fmaxf(mx, v); sm += v; }
        float mean = sm / (float)KEEP;
        if (gprev) {
            gfeat[(size_t)g*64 + t]      = gprev[(size_t)g*64 + t] + mx;
            gfeat[(size_t)g*64 + 32 + t] = gprev[(size_t)g*64 + 32 + t] + mean;
        } else {
            gfeat[(size_t)g*64 + t]      = mx;
            gfeat[(size_t)g*64 + 32 + t] = mean;
        }
    }
}

// ---- MLP head: 64 -> 256 -> 1024 -> 1, one graph per block, 4 ILP chains ----
__global__ __launch_bounds__(256) void k_mlp(const float* __restrict__ gsum,
    const float* __restrict__ W1, const float* __restrict__ b1,
    const float* __restrict__ W2, const float* __restrict__ b2,
    const float* __restrict__ W3, const float* __restrict__ b3,
    float* __restrict__ outp)
{
    int g = blockIdx.x, t = threadIdx.x;
    __shared__ float gL[64];
    __shared__ float h1L[256];
    __shared__ float red[256];
    if (t < 64) gL[t] = gsum[(size_t)g*64 + t];
    __syncthreads();
    float acc1 = b1[t];
    #pragma unroll
    for (int i = 0; i < 64; i++) acc1 = fmaf(gL[i], W1[i*256 + t], acc1);
    h1L[t] = fmaxf(acc1, 0.f);
    __syncthreads();
    float a0 = b2[t], a1 = b2[t + 256], a2 = b2[t + 512], a3 = b2[t + 768];
    #pragma unroll 4
    for (int i = 0; i < 256; i++) {
        float hv = h1L[i];
        const float* wr = W2 + (size_t)i*1024 + t;
        a0 = fmaf(hv, wr[0],   a0);
        a1 = fmaf(hv, wr[256], a1);
        a2 = fmaf(hv, wr[512], a2);
        a3 = fmaf(hv, wr[768], a3);
    }
    float p = fmaf(fmaxf(a0, 0.f), W3[t],
              fmaf(fmaxf(a1, 0.f), W3[t + 256],
              fmaf(fmaxf(a2, 0.f), W3[t + 512],
                   fmaxf(a3, 0.f) * W3[t + 768])));
    red[t] = p;
    __syncthreads();
    for (int s = 128; s > 0; s >>= 1) { if (t < s) red[t] += red[t + s]; __syncthreads(); }
    if (t == 0) outp[g] = red[0] + b3[0];
}

extern "C" void kernel_launch(void* const* d_in, const int* in_sizes, int n_in,
                              void* d_out, int out_size, void* d_ws, size_t ws_size,
                              hipStream_t stream)
{
    const float* x    = (const float*)d_in[0];
    const int*   ei   = (const int*)  d_in[1];
    const float* W_g1 = (const float*)d_in[4];
    const float* as1w = (const float*)d_in[5];
    const float* ad1w = (const float*)d_in[6];
    const float* b_g1 = (const float*)d_in[7];
    const float* W_t1 = (const float*)d_in[8];
    const float* b_t1 = (const float*)d_in[9];
    const float* pw1  = (const float*)d_in[10];
    const float* W_g2 = (const float*)d_in[11];
    const float* as2w = (const float*)d_in[12];
    const float* ad2w = (const float*)d_in[13];
    const float* b_g2 = (const float*)d_in[14];
    const float* W_t2 = (const float*)d_in[15];
    const float* b_t2 = (const float*)d_in[16];
    const float* pw2  = (const float*)d_in[17];
    const float* W_l1 = (const float*)d_in[18];
    const float* b_l1 = (const float*)d_in[19];
    const float* W_l2 = (const float*)d_in[20];
    const float* b_l2 = (const float*)d_in[21];
    const float* W_l3 = (const float*)d_in[22];
    const float* b_l3 = (const float*)d_in[23];
    float* out = (float*)d_out;

    char* ws = (char*)d_ws;
    size_t off = 0;
    auto alloc = [&](size_t elems) -> float* {
        float* p = (float*)(ws + off);
        off += ((elems * 4 + 255) / 256) * 256;
        return p;
    };
    float* xp1  = alloc((size_t)NN * FD);     // reused as hg2
    float* as1  = alloc((size_t)NN * 4);      // reused as as2
    float* ad1  = alloc((size_t)NN * 4);      // reused as ad2
    float* hg1  = alloc((size_t)NN * FD);     // reused as xp2
    float* ht1  = alloc((size_t)NN * HIDc);   // reused as ht2
    float* x2   = alloc((size_t)N2c * HIDc);
    int*   rank1= (int*)alloc((size_t)NN);
    float* g1   = alloc((size_t)NG * 64);
    float* gsum = alloc((size_t)NG * 64);
    float* wsS1 = alloc(64);
    float* wsD1 = alloc(64);
    float* wsS2 = alloc(128);
    float* wsD2 = alloc(128);
    float* xp2 = hg1;
    float* as2 = as1; float* ad2 = ad1;
    float* hg2 = xp1;
    float* ht2 = ht1;

    k_fold<IND> <<<1, 64, 0, stream>>>(W_g1, as1w, ad1w, wsS1, wsD1);
    k_fold<HIDc><<<1, 128, 0, stream>>>(W_g2, as2w, ad2w, wsS2, wsD2);

    k_proj<IND><<<NN/32, 256, 0, stream>>>(x, W_g1, wsS1, wsD1, xp1, as1, ad1);
    k_gat<NPGc, false><<<dim3(NG, 4), 256, 0, stream>>>(ei, nullptr, xp1, as1, ad1, b_g1, hg1);
    k_lin<<<NN/32, 256, 0, stream>>>(hg1, W_t1, b_t1, ht1);
    k_pool<NPGc, K1c><<<NG, 128, 0, stream>>>(ht1, pw1, x2, rank1, g1, nullptr);

    k_proj<HIDc><<<N2c/32, 256, 0, stream>>>(x2, W_g2, wsS2, wsD2, xp2, as2, ad2);
    k_gat<K1c, true><<<dim3(NG, 4), 256, 0, stream>>>(ei, rank1, xp2, as2, ad2, b_g2, hg2);
    k_lin<<<N2c/32, 256, 0, stream>>>(hg2, W_t2, b_t2, ht2);
    k_pool<K1c, K2c><<<NG, 128, 0, stream>>>(ht2, pw2, nullptr, nullptr, gsum, g1);

    k_mlp<<<NG, 256, 0, stream>>>(gsum, W_l1, b_l1, W_l2, b_l2, W_l3, b_l3, out);
}